// Round 7
// baseline (207.158 us; speedup 1.0000x reference)
//
#include <hip/hip_runtime.h>
#include <cstdint>
#include <cstddef>

#define NCH 128
#define SCAN_CHUNK 2048  // 256 threads x 8 elems
#define GEMM_ROWS 64
#define XPAD 136         // 128 + 8 bf16 pad: A-frag ds_read_b128 is conflict-free

typedef short bf16x8 __attribute__((ext_vector_type(8)));
typedef float f32x4 __attribute__((ext_vector_type(4)));

__device__ __forceinline__ int detect_is64(const unsigned int* __restrict__ ei) {
  // int64 edge_index with ids < 2^31 -> all odd 32-bit words zero. Wave-uniform;
  // call with all lanes active.
  unsigned int v = ei[((threadIdx.x & 63) << 1) + 1];
  return (__ballot(v != 0u) == 0ULL) ? 1 : 0;
}

__device__ __forceinline__ unsigned short f2bf(float x) {
  unsigned int u = __float_as_uint(x);
  u += 0x7fffu + ((u >> 16) & 1u);  // RNE
  return (unsigned short)(u >> 16);
}

// Blocks 0..63: transpose W -> bf16 wt[n][k]. Blocks 64..79: zero counts+flags.
__global__ __launch_bounds__(256) void k_prep(const float* __restrict__ W,
                                              unsigned short* __restrict__ wt,
                                              int4* __restrict__ zbase, int nz4) {
  if ((int)blockIdx.x < 64) {
    int idx = blockIdx.x * 256 + threadIdx.x;  // 0..16383
    int n = idx >> 7, k = idx & 127;
    wt[idx] = f2bf(W[k * NCH + n]);
  } else {
    int4 z = make_int4(0, 0, 0, 0);
    for (int i = (blockIdx.x - 64) * 256 + threadIdx.x; i < nz4; i += 16 * 256)
      zbase[i] = z;
  }
}

// Fused front: blocks [0,gbl) do the MFMA GEMM (g = bf16(x@W), UNSCALED — dis is
// applied per-edge in k_agg); blocks [gbl,..) do degree count (1 edge/thread).
// The two roles are independent -> MFMA and atomic/memory pipes overlap (m114).
__global__ __launch_bounds__(256) void k_front(const float* __restrict__ x,
                                               const unsigned short* __restrict__ wt,
                                               unsigned short* __restrict__ g, int N,
                                               const void* __restrict__ ei, int E,
                                               int gbl, int* __restrict__ counts) {
  if ((int)blockIdx.x >= gbl) {
    // ---- count role ----
    int is64 = detect_is64((const unsigned int*)ei);
    int e = (blockIdx.x - gbl) * 256 + threadIdx.x;
    if (e < E) {
      int d = is64 ? (int)((const long long*)ei)[(long long)E + e]
                   : ((const int*)ei)[(long long)E + e];
      atomicAdd(&counts[d], 1);
    }
    return;
  }
  // ---- gemm role: 64 rows/block, 4 waves; wave w -> cols [32w,32w+32) ----
  __shared__ unsigned short xbf[GEMM_ROWS * XPAD];
  int t = threadIdx.x;
  int row0 = blockIdx.x * GEMM_ROWS;

#pragma unroll
  for (int j = 0; j < 8; ++j) {
    int idx = t + 256 * j;      // 0..2047
    int r = idx >> 5;           // row 0..63
    int ch = idx & 31;          // float4 chunk
    int row = row0 + r;
    float4 v = (row < N) ? ((const float4*)(x + (size_t)row * NCH))[ch]
                         : make_float4(0.f, 0.f, 0.f, 0.f);
    ushort4 p;
    p.x = f2bf(v.x); p.y = f2bf(v.y); p.z = f2bf(v.z); p.w = f2bf(v.w);
    *(ushort4*)&xbf[r * XPAD + ch * 4] = p;
  }

  int lane = t & 63;
  int wv = t >> 6;
  int n0 = wv * 32;
  int l15 = lane & 15;
  int q = lane >> 4;  // 0..3

  bf16x8 B[4][2];
#pragma unroll
  for (int ks = 0; ks < 4; ++ks)
#pragma unroll
    for (int nt = 0; nt < 2; ++nt) {
      int n = n0 + nt * 16 + l15;
      B[ks][nt] = *(const bf16x8*)(wt + (size_t)n * NCH + ks * 32 + q * 8);
    }

  __syncthreads();

  f32x4 acc[4][2];
#pragma unroll
  for (int mt = 0; mt < 4; ++mt)
#pragma unroll
    for (int nt = 0; nt < 2; ++nt)
#pragma unroll
      for (int i = 0; i < 4; ++i) acc[mt][nt][i] = 0.f;

#pragma unroll
  for (int ks = 0; ks < 4; ++ks) {
#pragma unroll
    for (int mt = 0; mt < 4; ++mt) {
      bf16x8 a = *(const bf16x8*)&xbf[(mt * 16 + l15) * XPAD + ks * 32 + q * 8];
      acc[mt][0] = __builtin_amdgcn_mfma_f32_16x16x32_bf16(a, B[ks][0], acc[mt][0], 0, 0, 0);
      acc[mt][1] = __builtin_amdgcn_mfma_f32_16x16x32_bf16(a, B[ks][1], acc[mt][1], 0, 0, 0);
    }
  }

#pragma unroll
  for (int mt = 0; mt < 4; ++mt) {
#pragma unroll
    for (int reg = 0; reg < 4; ++reg) {
      int rl = mt * 16 + q * 4 + reg;
      int row = row0 + rl;
      if (row < N) {
        size_t base = (size_t)row * NCH + n0;
        g[base + l15]      = f2bf(acc[mt][0][reg]);
        g[base + 16 + l15] = f2bf(acc[mt][1][reg]);
      }
    }
  }
}

// Single-pass exclusive scan (decoupled lookback): row_ptr[i+1], cursor[i]
// (= exclusive prefix, consumed by k_fill's atomics), dis[i] = rsqrt(deg+1).
__global__ __launch_bounds__(256) void k_scan(const int* __restrict__ counts, int N,
                                              unsigned long long* __restrict__ flagsum,
                                              int* __restrict__ row_ptr,
                                              int* __restrict__ cursor,
                                              float* __restrict__ dis) {
  int t = threadIdx.x;
  int base = blockIdx.x * SCAN_CHUNK + t * 8;
  int v[8];
  int s = 0;
  if (base + 8 <= N) {
    const int4* p = (const int4*)(counts + base);
    int4 a = p[0], b = p[1];
    v[0] = a.x; v[1] = a.y; v[2] = a.z; v[3] = a.w;
    v[4] = b.x; v[5] = b.y; v[6] = b.z; v[7] = b.w;
  } else {
#pragma unroll
    for (int j = 0; j < 8; ++j) {
      int i = base + j;
      v[j] = (i < N) ? counts[i] : 0;
    }
  }
#pragma unroll
  for (int j = 0; j < 8; ++j) s += v[j];

  int lane = t & 63, w = t >> 6;
  int incl = s;
#pragma unroll
  for (int off = 1; off < 64; off <<= 1) {
    int o = __shfl_up(incl, off);
    if (lane >= off) incl += o;
  }
  __shared__ int wsum[4];
  __shared__ int s_boff;
  if (lane == 63) wsum[w] = incl;
  __syncthreads();

  if (t == 0) {
    int btot = (wsum[0] + wsum[1]) + (wsum[2] + wsum[3]);
    unsigned long long pub = (1ull << 63) | (unsigned int)btot;
    __hip_atomic_store(&flagsum[blockIdx.x], pub, __ATOMIC_RELEASE,
                       __HIP_MEMORY_SCOPE_AGENT);
    int acc = 0;
    for (int i = (int)blockIdx.x - 1; i >= 0; --i) {
      unsigned long long fv;
      do {
        fv = __hip_atomic_load(&flagsum[i], __ATOMIC_ACQUIRE,
                               __HIP_MEMORY_SCOPE_AGENT);
      } while (!(fv >> 63));
      acc += (int)(unsigned int)fv;
    }
    s_boff = acc;
  }
  __syncthreads();

  int woff = 0;
#pragma unroll
  for (int k = 0; k < 4; ++k)
    if (k < w) woff += wsum[k];

  int run = s_boff + woff + (incl - s);
#pragma unroll
  for (int j = 0; j < 8; ++j) {
    int i = base + j;
    if (i < N) cursor[i] = run;
    run += v[j];
    if (i < N) {
      row_ptr[i + 1] = run;
      dis[i] = rsqrtf((float)(v[j] + 1));  // +1 self-loop; always > 0
    }
  }
  if (blockIdx.x == 0 && t == 0) row_ptr[0] = 0;
}

// CSR fill via cursor atomics (1 edge/thread — max occupancy for latency hiding).
__global__ __launch_bounds__(256) void k_fill(const void* __restrict__ ei, int E,
                                              int* __restrict__ cursor,
                                              int* __restrict__ edge_src) {
  int is64 = detect_is64((const unsigned int*)ei);
  int e = blockIdx.x * 256 + threadIdx.x;
  if (e >= E) return;
  int s, d;
  if (is64) {
    s = (int)((const long long*)ei)[e];
    d = (int)((const long long*)ei)[(long long)E + e];
  } else {
    s = ((const int*)ei)[e];
    d = ((const int*)ei)[(long long)E + e];
  }
  edge_src[atomicAdd(&cursor[d], 1)] = s;
}

// One wave per node, edge-pair loads: lane L -> half h=L>>5 (edge e+h), sublane
// sl=L&31 -> channels [4sl,4sl+4) as uint2 (4 bf16). g is UNSCALED h; each
// gathered row is weighted by dis[s] (L2-hot 200KB table, wave-broadcast load).
__global__ __launch_bounds__(256) void k_agg(const unsigned short* __restrict__ g,
                                             const int* __restrict__ row_ptr,
                                             const int* __restrict__ edge_src,
                                             const float* __restrict__ dis,
                                             const float* __restrict__ bias,
                                             float* __restrict__ out, int N) {
  int i = blockIdx.x * 4 + (threadIdx.x >> 6);
  if (i >= N) return;
  int lane = threadIdx.x & 63;
  int h = lane >> 5, sl = lane & 31;
  float di = dis[i];

  float a0 = 0.f, a1 = 0.f, a2 = 0.f, a3 = 0.f;
  // self-loop term di*h[i]: half 0 only
  if (h == 0) {
    uint2 v = *(const uint2*)(g + (size_t)i * NCH + sl * 4);
    a0 = di * __uint_as_float(v.x << 16);
    a1 = di * __uint_as_float(v.x & 0xffff0000u);
    a2 = di * __uint_as_float(v.y << 16);
    a3 = di * __uint_as_float(v.y & 0xffff0000u);
  }

  int e = row_ptr[i];
  int end = row_ptr[i + 1];
  for (; e + 8 <= end; e += 8) {
    int s0 = edge_src[e + h];
    int s1 = edge_src[e + 2 + h];
    int s2 = edge_src[e + 4 + h];
    int s3 = edge_src[e + 6 + h];
    float d0 = dis[s0], d1 = dis[s1], d2 = dis[s2], d3 = dis[s3];
    uint2 v0 = *(const uint2*)(g + (size_t)s0 * NCH + sl * 4);
    uint2 v1 = *(const uint2*)(g + (size_t)s1 * NCH + sl * 4);
    uint2 v2 = *(const uint2*)(g + (size_t)s2 * NCH + sl * 4);
    uint2 v3 = *(const uint2*)(g + (size_t)s3 * NCH + sl * 4);
    a0 = fmaf(d0, __uint_as_float(v0.x << 16), a0);
    a1 = fmaf(d0, __uint_as_float(v0.x & 0xffff0000u), a1);
    a2 = fmaf(d0, __uint_as_float(v0.y << 16), a2);
    a3 = fmaf(d0, __uint_as_float(v0.y & 0xffff0000u), a3);
    a0 = fmaf(d1, __uint_as_float(v1.x << 16), a0);
    a1 = fmaf(d1, __uint_as_float(v1.x & 0xffff0000u), a1);
    a2 = fmaf(d1, __uint_as_float(v1.y << 16), a2);
    a3 = fmaf(d1, __uint_as_float(v1.y & 0xffff0000u), a3);
    a0 = fmaf(d2, __uint_as_float(v2.x << 16), a0);
    a1 = fmaf(d2, __uint_as_float(v2.x & 0xffff0000u), a1);
    a2 = fmaf(d2, __uint_as_float(v2.y << 16), a2);
    a3 = fmaf(d2, __uint_as_float(v2.y & 0xffff0000u), a3);
    a0 = fmaf(d3, __uint_as_float(v3.x << 16), a0);
    a1 = fmaf(d3, __uint_as_float(v3.x & 0xffff0000u), a1);
    a2 = fmaf(d3, __uint_as_float(v3.y << 16), a2);
    a3 = fmaf(d3, __uint_as_float(v3.y & 0xffff0000u), a3);
  }
  for (; e < end; e += 2) {
    int idx = e + h;
    if (idx < end) {
      int s = edge_src[idx];
      float ds = dis[s];
      uint2 v = *(const uint2*)(g + (size_t)s * NCH + sl * 4);
      a0 = fmaf(ds, __uint_as_float(v.x << 16), a0);
      a1 = fmaf(ds, __uint_as_float(v.x & 0xffff0000u), a1);
      a2 = fmaf(ds, __uint_as_float(v.y << 16), a2);
      a3 = fmaf(ds, __uint_as_float(v.y & 0xffff0000u), a3);
    }
  }

  a0 += __shfl_xor(a0, 32);
  a1 += __shfl_xor(a1, 32);
  a2 += __shfl_xor(a2, 32);
  a3 += __shfl_xor(a3, 32);

  if (h == 0) {
    float4 bb = ((const float4*)bias)[sl];
    f32x4 o;
    o[0] = fmaxf(fmaf(a0, di, bb.x), 0.f);
    o[1] = fmaxf(fmaf(a1, di, bb.y), 0.f);
    o[2] = fmaxf(fmaf(a2, di, bb.z), 0.f);
    o[3] = fmaxf(fmaf(a3, di, bb.w), 0.f);
    __builtin_nontemporal_store(o, (f32x4*)(out + (size_t)i * NCH + sl * 4));
  }
}

extern "C" void kernel_launch(void* const* d_in, const int* in_sizes, int n_in,
                              void* d_out, int out_size, void* d_ws, size_t ws_size,
                              hipStream_t stream) {
  const float* x    = (const float*)d_in[0];
  const void*  ei   = d_in[1];
  const float* W    = (const float*)d_in[2];
  const float* bias = (const float*)d_in[3];
  float* out = (float*)d_out;

  int N = out_size / NCH;       // 50000
  int E = in_sizes[1] / 2;      // 800000

  char* ws = (char*)d_ws;
  size_t off = 0;
  auto alloc = [&](size_t bytes) -> char* {
    char* p = ws + off;
    off = (off + bytes + 255) & ~(size_t)255;
    return p;
  };
  // zeroed region (by k_prep): counts + flagsum
  char* zbase = ws;
  int*                counts  = (int*)alloc((size_t)N * 4);
  unsigned long long* flagsum = (unsigned long long*)alloc(1024);
  size_t zbytes = off;  // 256-aligned
  int*            row_ptr  = (int*)alloc((size_t)(N + 1) * 4);
  int*            cursor   = (int*)alloc((size_t)N * 4);
  float*          dis      = (float*)alloc((size_t)N * 4);
  unsigned short* wt       = (unsigned short*)alloc((size_t)NCH * NCH * 2);
  int*            edge_src = (int*)alloc((size_t)E * 4);
  unsigned short* g        = (unsigned short*)alloc((size_t)N * NCH * 2);
  (void)ws_size;

  int nb  = (N + SCAN_CHUNK - 1) / SCAN_CHUNK;  // 25
  int gbl = (N + GEMM_ROWS - 1) / GEMM_ROWS;    // 782 gemm blocks
  int cbl = (E + 255) / 256;                    // 3125 count/fill blocks
  int nz4 = (int)(zbytes / 16);

  k_prep<<<80, 256, 0, stream>>>(W, wt, (int4*)zbase, nz4);
  k_front<<<gbl + cbl, 256, 0, stream>>>(x, wt, g, N, ei, E, gbl, counts);
  k_scan<<<nb, 256, 0, stream>>>(counts, N, flagsum, row_ptr, cursor, dis);
  k_fill<<<cbl, 256, 0, stream>>>(ei, E, cursor, edge_src);
  k_agg<<<(N + 3) / 4, 256, 0, stream>>>(g, row_ptr, edge_src, dis, bias, out, N);
}

// Round 8
// 180.365 us; speedup vs baseline: 1.1485x; 1.1485x over previous
//
#include <hip/hip_runtime.h>
#include <cstdint>
#include <cstddef>

#define NCH 128
#define SCAN_CHUNK 2048  // 256 threads x 8 elems
#define GEMM_ROWS 64
#define XPAD 136         // 128 + 8 bf16 pad: A-frag ds_read_b128 is conflict-free

typedef short bf16x8 __attribute__((ext_vector_type(8)));
typedef float f32x4 __attribute__((ext_vector_type(4)));

__device__ __forceinline__ int detect_is64(const unsigned int* __restrict__ ei) {
  // int64 edge_index with ids < 2^31 -> all odd 32-bit words zero. Wave-uniform;
  // call with all lanes active.
  unsigned int v = ei[((threadIdx.x & 63) << 1) + 1];
  return (__ballot(v != 0u) == 0ULL) ? 1 : 0;
}

__device__ __forceinline__ unsigned short f2bf(float x) {
  unsigned int u = __float_as_uint(x);
  u += 0x7fffu + ((u >> 16) & 1u);  // RNE
  return (unsigned short)(u >> 16);
}

// Blocks 0..63: transpose W -> bf16 wt[n][k]. Blocks 64..79: zero counts+flags.
__global__ __launch_bounds__(256) void k_prep(const float* __restrict__ W,
                                              unsigned short* __restrict__ wt,
                                              int4* __restrict__ zbase, int nz4) {
  if ((int)blockIdx.x < 64) {
    int idx = blockIdx.x * 256 + threadIdx.x;  // 0..16383
    int n = idx >> 7, k = idx & 127;
    wt[idx] = f2bf(W[k * NCH + n]);
  } else {
    int4 z = make_int4(0, 0, 0, 0);
    for (int i = (blockIdx.x - 64) * 256 + threadIdx.x; i < nz4; i += 16 * 256)
      zbase[i] = z;
  }
}

// Degree count, 1 edge/thread; rank[e] = arrival order at destination
// (independent loads in k_fill later — NO atomic on the fill critical path).
__global__ __launch_bounds__(256) void k_count(const void* __restrict__ ei, int E,
                                               int* __restrict__ counts,
                                               int* __restrict__ rank) {
  int is64 = detect_is64((const unsigned int*)ei);
  int e = blockIdx.x * 256 + threadIdx.x;
  if (e < E) {
    int d = is64 ? (int)((const long long*)ei)[(long long)E + e]
                 : ((const int*)ei)[(long long)E + e];
    rank[e] = atomicAdd(&counts[d], 1);
  }
}

// Single-pass exclusive scan (decoupled lookback): row_ptr[i+1],
// dis[i] = rsqrt(deg+1).
__global__ __launch_bounds__(256) void k_scan(const int* __restrict__ counts, int N,
                                              unsigned long long* __restrict__ flagsum,
                                              int* __restrict__ row_ptr,
                                              float* __restrict__ dis) {
  int t = threadIdx.x;
  int base = blockIdx.x * SCAN_CHUNK + t * 8;
  int v[8];
  int s = 0;
  if (base + 8 <= N) {
    const int4* p = (const int4*)(counts + base);
    int4 a = p[0], b = p[1];
    v[0] = a.x; v[1] = a.y; v[2] = a.z; v[3] = a.w;
    v[4] = b.x; v[5] = b.y; v[6] = b.z; v[7] = b.w;
  } else {
#pragma unroll
    for (int j = 0; j < 8; ++j) {
      int i = base + j;
      v[j] = (i < N) ? counts[i] : 0;
    }
  }
#pragma unroll
  for (int j = 0; j < 8; ++j) s += v[j];

  int lane = t & 63, w = t >> 6;
  int incl = s;
#pragma unroll
  for (int off = 1; off < 64; off <<= 1) {
    int o = __shfl_up(incl, off);
    if (lane >= off) incl += o;
  }
  __shared__ int wsum[4];
  __shared__ int s_boff;
  if (lane == 63) wsum[w] = incl;
  __syncthreads();

  if (t == 0) {
    int btot = (wsum[0] + wsum[1]) + (wsum[2] + wsum[3]);
    unsigned long long pub = (1ull << 63) | (unsigned int)btot;
    __hip_atomic_store(&flagsum[blockIdx.x], pub, __ATOMIC_RELEASE,
                       __HIP_MEMORY_SCOPE_AGENT);
    int acc = 0;
    for (int i = (int)blockIdx.x - 1; i >= 0; --i) {
      unsigned long long fv;
      do {
        fv = __hip_atomic_load(&flagsum[i], __ATOMIC_ACQUIRE,
                               __HIP_MEMORY_SCOPE_AGENT);
      } while (!(fv >> 63));
      acc += (int)(unsigned int)fv;
    }
    s_boff = acc;
  }
  __syncthreads();

  int woff = 0;
#pragma unroll
  for (int k = 0; k < 4; ++k)
    if (k < w) woff += wsum[k];

  int run = s_boff + woff + (incl - s);
#pragma unroll
  for (int j = 0; j < 8; ++j) {
    run += v[j];
    int i = base + j;
    if (i < N) {
      row_ptr[i + 1] = run;
      dis[i] = rsqrtf((float)(v[j] + 1));  // +1 self-loop; always > 0
    }
  }
  if (blockIdx.x == 0 && t == 0) row_ptr[0] = 0;
}

// Fused back-mid: blocks [0,gbl) = MFMA GEMM g[i,:]=bf16(dis[i]*(x@W));
// blocks [gbl,..) = rank-based CSR fill. Independent roles -> MFMA pipe
// overlaps the fill's memory/scatter time (m114 co-scheduling).
__global__ __launch_bounds__(256) void k_front(const float* __restrict__ x,
                                               const unsigned short* __restrict__ wt,
                                               const float* __restrict__ dis,
                                               unsigned short* __restrict__ g, int N,
                                               const void* __restrict__ ei, int E,
                                               const int* __restrict__ rank,
                                               const int* __restrict__ row_ptr,
                                               int* __restrict__ edge_src, int gbl) {
  if ((int)blockIdx.x >= gbl) {
    // ---- fill role (1 edge/thread, no atomics) ----
    int is64 = detect_is64((const unsigned int*)ei);
    int e = (blockIdx.x - gbl) * 256 + threadIdx.x;
    if (e < E) {
      int s, d;
      if (is64) {
        s = (int)((const long long*)ei)[e];
        d = (int)((const long long*)ei)[(long long)E + e];
      } else {
        s = ((const int*)ei)[e];
        d = ((const int*)ei)[(long long)E + e];
      }
      edge_src[row_ptr[d] + rank[e]] = s;
    }
    return;
  }
  // ---- gemm role: 64 rows/block, 4 waves; wave w -> cols [32w,32w+32) ----
  __shared__ unsigned short xbf[GEMM_ROWS * XPAD];
  __shared__ float sdis[GEMM_ROWS];
  int t = threadIdx.x;
  int row0 = blockIdx.x * GEMM_ROWS;

#pragma unroll
  for (int j = 0; j < 8; ++j) {
    int idx = t + 256 * j;      // 0..2047
    int r = idx >> 5;           // row 0..63
    int ch = idx & 31;          // float4 chunk
    int row = row0 + r;
    float4 v = (row < N) ? ((const float4*)(x + (size_t)row * NCH))[ch]
                         : make_float4(0.f, 0.f, 0.f, 0.f);
    ushort4 p;
    p.x = f2bf(v.x); p.y = f2bf(v.y); p.z = f2bf(v.z); p.w = f2bf(v.w);
    *(ushort4*)&xbf[r * XPAD + ch * 4] = p;
  }
  if (t < GEMM_ROWS) {
    int row = row0 + t;
    sdis[t] = (row < N) ? dis[row] : 0.f;
  }

  int lane = t & 63;
  int wv = t >> 6;
  int n0 = wv * 32;
  int l15 = lane & 15;
  int q = lane >> 4;  // 0..3

  bf16x8 B[4][2];
#pragma unroll
  for (int ks = 0; ks < 4; ++ks)
#pragma unroll
    for (int nt = 0; nt < 2; ++nt) {
      int n = n0 + nt * 16 + l15;
      B[ks][nt] = *(const bf16x8*)(wt + (size_t)n * NCH + ks * 32 + q * 8);
    }

  __syncthreads();

  f32x4 acc[4][2];
#pragma unroll
  for (int mt = 0; mt < 4; ++mt)
#pragma unroll
    for (int nt = 0; nt < 2; ++nt)
#pragma unroll
      for (int i = 0; i < 4; ++i) acc[mt][nt][i] = 0.f;

#pragma unroll
  for (int ks = 0; ks < 4; ++ks) {
#pragma unroll
    for (int mt = 0; mt < 4; ++mt) {
      bf16x8 a = *(const bf16x8*)&xbf[(mt * 16 + l15) * XPAD + ks * 32 + q * 8];
      acc[mt][0] = __builtin_amdgcn_mfma_f32_16x16x32_bf16(a, B[ks][0], acc[mt][0], 0, 0, 0);
      acc[mt][1] = __builtin_amdgcn_mfma_f32_16x16x32_bf16(a, B[ks][1], acc[mt][1], 0, 0, 0);
    }
  }

#pragma unroll
  for (int mt = 0; mt < 4; ++mt) {
#pragma unroll
    for (int reg = 0; reg < 4; ++reg) {
      int rl = mt * 16 + q * 4 + reg;
      int row = row0 + rl;
      if (row < N) {
        float dl = sdis[rl];
        size_t base = (size_t)row * NCH + n0;
        g[base + l15]      = f2bf(acc[mt][0][reg] * dl);
        g[base + 16 + l15] = f2bf(acc[mt][1][reg] * dl);
      }
    }
  }
}

// One wave per node, edge-pair loads: lane L -> half h=L>>5 (edge e+h), sublane
// sl=L&31 -> channels [4sl,4sl+4) as uint2 (4 bf16). g is pre-scaled by dis[src].
__global__ __launch_bounds__(256) void k_agg(const unsigned short* __restrict__ g,
                                             const int* __restrict__ row_ptr,
                                             const int* __restrict__ edge_src,
                                             const float* __restrict__ dis,
                                             const float* __restrict__ bias,
                                             float* __restrict__ out, int N) {
  int i = blockIdx.x * 4 + (threadIdx.x >> 6);
  if (i >= N) return;
  int lane = threadIdx.x & 63;
  int h = lane >> 5, sl = lane & 31;

  float a0 = 0.f, a1 = 0.f, a2 = 0.f, a3 = 0.f;
  // self-loop term: half 0 only
  if (h == 0) {
    uint2 v = *(const uint2*)(g + (size_t)i * NCH + sl * 4);
    a0 = __uint_as_float(v.x << 16);
    a1 = __uint_as_float(v.x & 0xffff0000u);
    a2 = __uint_as_float(v.y << 16);
    a3 = __uint_as_float(v.y & 0xffff0000u);
  }

  int e = row_ptr[i];
  int end = row_ptr[i + 1];
  for (; e + 8 <= end; e += 8) {
    int s0 = edge_src[e + h];
    int s1 = edge_src[e + 2 + h];
    int s2 = edge_src[e + 4 + h];
    int s3 = edge_src[e + 6 + h];
    uint2 v0 = *(const uint2*)(g + (size_t)s0 * NCH + sl * 4);
    uint2 v1 = *(const uint2*)(g + (size_t)s1 * NCH + sl * 4);
    uint2 v2 = *(const uint2*)(g + (size_t)s2 * NCH + sl * 4);
    uint2 v3 = *(const uint2*)(g + (size_t)s3 * NCH + sl * 4);
    a0 += (__uint_as_float(v0.x << 16) + __uint_as_float(v1.x << 16)) +
          (__uint_as_float(v2.x << 16) + __uint_as_float(v3.x << 16));
    a1 += (__uint_as_float(v0.x & 0xffff0000u) + __uint_as_float(v1.x & 0xffff0000u)) +
          (__uint_as_float(v2.x & 0xffff0000u) + __uint_as_float(v3.x & 0xffff0000u));
    a2 += (__uint_as_float(v0.y << 16) + __uint_as_float(v1.y << 16)) +
          (__uint_as_float(v2.y << 16) + __uint_as_float(v3.y << 16));
    a3 += (__uint_as_float(v0.y & 0xffff0000u) + __uint_as_float(v1.y & 0xffff0000u)) +
          (__uint_as_float(v2.y & 0xffff0000u) + __uint_as_float(v3.y & 0xffff0000u));
  }
  for (; e < end; e += 2) {
    int idx = e + h;
    if (idx < end) {
      uint2 v = *(const uint2*)(g + (size_t)edge_src[idx] * NCH + sl * 4);
      a0 += __uint_as_float(v.x << 16);
      a1 += __uint_as_float(v.x & 0xffff0000u);
      a2 += __uint_as_float(v.y << 16);
      a3 += __uint_as_float(v.y & 0xffff0000u);
    }
  }

  a0 += __shfl_xor(a0, 32);
  a1 += __shfl_xor(a1, 32);
  a2 += __shfl_xor(a2, 32);
  a3 += __shfl_xor(a3, 32);

  if (h == 0) {
    float di = dis[i];
    float4 bb = ((const float4*)bias)[sl];
    f32x4 o;
    o[0] = fmaxf(fmaf(a0, di, bb.x), 0.f);
    o[1] = fmaxf(fmaf(a1, di, bb.y), 0.f);
    o[2] = fmaxf(fmaf(a2, di, bb.z), 0.f);
    o[3] = fmaxf(fmaf(a3, di, bb.w), 0.f);
    __builtin_nontemporal_store(o, (f32x4*)(out + (size_t)i * NCH + sl * 4));
  }
}

extern "C" void kernel_launch(void* const* d_in, const int* in_sizes, int n_in,
                              void* d_out, int out_size, void* d_ws, size_t ws_size,
                              hipStream_t stream) {
  const float* x    = (const float*)d_in[0];
  const void*  ei   = d_in[1];
  const float* W    = (const float*)d_in[2];
  const float* bias = (const float*)d_in[3];
  float* out = (float*)d_out;

  int N = out_size / NCH;       // 50000
  int E = in_sizes[1] / 2;      // 800000

  char* ws = (char*)d_ws;
  size_t off = 0;
  auto alloc = [&](size_t bytes) -> char* {
    char* p = ws + off;
    off = (off + bytes + 255) & ~(size_t)255;
    return p;
  };
  // zeroed region (by k_prep): counts + flagsum
  char* zbase = ws;
  int*                counts  = (int*)alloc((size_t)N * 4);
  unsigned long long* flagsum = (unsigned long long*)alloc(1024);
  size_t zbytes = off;  // 256-aligned
  int*            row_ptr  = (int*)alloc((size_t)(N + 1) * 4);
  float*          dis      = (float*)alloc((size_t)N * 4);
  unsigned short* wt       = (unsigned short*)alloc((size_t)NCH * NCH * 2);
  int*            rank     = (int*)alloc((size_t)E * 4);
  int*            edge_src = (int*)alloc((size_t)E * 4);
  unsigned short* g        = (unsigned short*)alloc((size_t)N * NCH * 2);
  (void)ws_size;

  int nb  = (N + SCAN_CHUNK - 1) / SCAN_CHUNK;  // 25
  int gbl = (N + GEMM_ROWS - 1) / GEMM_ROWS;    // 782 gemm blocks
  int cbl = (E + 255) / 256;                    // 3125 count/fill blocks
  int nz4 = (int)(zbytes / 16);

  k_prep<<<80, 256, 0, stream>>>(W, wt, (int4*)zbase, nz4);
  k_count<<<cbl, 256, 0, stream>>>(ei, E, counts, rank);
  k_scan<<<nb, 256, 0, stream>>>(counts, N, flagsum, row_ptr, dis);
  k_front<<<gbl + cbl, 256, 0, stream>>>(x, wt, dis, g, N, ei, E, rank, row_ptr,
                                         edge_src, gbl);
  k_agg<<<(N + 3) / 4, 256, 0, stream>>>(g, row_ptr, edge_src, dis, bias, out, N);
}

// Round 10
// 179.657 us; speedup vs baseline: 1.1531x; 1.0039x over previous
//
#include <hip/hip_runtime.h>
#include <hip/hip_cooperative_groups.h>
#include <cstdint>
#include <cstddef>

namespace cg = cooperative_groups;

#define NCH 128
#define GRID 1024        // 4 blocks/CU x 256 CUs
#define SCAN_CHUNK 2048  // 256 threads x 8 elems
#define GEMM_ROWS 64
#define XPAD 136         // 128 + 8 bf16 pad: A-frag ds_read_b128 conflict-free
#define EMAX 14          // max edges/thread on count blocks (ceil(800000/61952)=13)

typedef short bf16x8 __attribute__((ext_vector_type(8)));
typedef float f32x4 __attribute__((ext_vector_type(4)));

__device__ __forceinline__ int detect_is64(const unsigned int* __restrict__ ei) {
  // int64 edge_index with ids < 2^31 -> all odd 32-bit words zero. Wave-uniform;
  // call with all lanes active (kernel top, before divergence).
  unsigned int v = ei[((threadIdx.x & 63) << 1) + 1];
  return (__ballot(v != 0u) == 0ULL) ? 1 : 0;
}

__device__ __forceinline__ unsigned short f2bf(float x) {
  unsigned int u = __float_as_uint(x);
  u += 0x7fffu + ((u >> 16) & 1u);  // RNE
  return (unsigned short)(u >> 16);
}

__device__ __forceinline__ int ei_at(const void* ei, long long i, int is64) {
  return is64 ? (int)((const long long*)ei)[i] : ((const int*)ei)[i];
}

// ======================= cooperative mega-kernel =======================
__global__ __launch_bounds__(256, 4) void k_mega(
    const float* __restrict__ x, const void* __restrict__ ei,
    const float* __restrict__ W, const float* __restrict__ bias,
    float* __restrict__ out, int N, int E, int ntiles, int gbl,
    int* __restrict__ counts, unsigned long long* __restrict__ flagsum,
    int* __restrict__ row_ptr, float* __restrict__ dis,
    unsigned short* __restrict__ wt, int* __restrict__ edge_src,
    unsigned short* __restrict__ g) {
  cg::grid_group grid = cg::this_grid();
  const int b = blockIdx.x, t = threadIdx.x;
  const int tid = b * 256 + t;

  __shared__ unsigned short xbf[GEMM_ROWS * XPAD];
  __shared__ int wsum[4];
  __shared__ int s_boff;

  const int is64 = detect_is64((const unsigned int*)ei);

  // -------- Phase A: zero counts/flags, transpose W --------
  for (int i = tid; i < N; i += GRID * 256) counts[i] = 0;
  if (tid < 64) flagsum[tid] = 0;
  for (int i = tid; i < NCH * NCH; i += GRID * 256) {
    int n = i >> 7, k = i & 127;
    wt[i] = f2bf(W[k * NCH + n]);
  }
  grid.sync();

  // -------- Phase B: gemm (unscaled) || count (ranks in regs) --------
  const int CT = (GRID - gbl) * 256;
  int nranks[EMAX];
  if (b < gbl) {
    const int lane = t & 63, wv = t >> 6;
    const int n0 = wv * 32, l15 = lane & 15, q = lane >> 4;
    bf16x8 B[4][2];
#pragma unroll
    for (int ks = 0; ks < 4; ++ks)
#pragma unroll
      for (int nt = 0; nt < 2; ++nt) {
        int n = n0 + nt * 16 + l15;
        B[ks][nt] = *(const bf16x8*)(wt + (size_t)n * NCH + ks * 32 + q * 8);
      }
    for (int tile = b; tile < ntiles; tile += gbl) {
      int row0 = tile * GEMM_ROWS;
      __syncthreads();
#pragma unroll
      for (int j = 0; j < 8; ++j) {
        int idx = t + 256 * j;
        int r = idx >> 5, ch = idx & 31;
        int row = row0 + r;
        float4 v = (row < N) ? ((const float4*)(x + (size_t)row * NCH))[ch]
                             : make_float4(0.f, 0.f, 0.f, 0.f);
        ushort4 p;
        p.x = f2bf(v.x); p.y = f2bf(v.y); p.z = f2bf(v.z); p.w = f2bf(v.w);
        *(ushort4*)&xbf[r * XPAD + ch * 4] = p;
      }
      __syncthreads();
      f32x4 acc[4][2];
#pragma unroll
      for (int mt = 0; mt < 4; ++mt)
#pragma unroll
        for (int nt = 0; nt < 2; ++nt)
#pragma unroll
          for (int i = 0; i < 4; ++i) acc[mt][nt][i] = 0.f;
#pragma unroll
      for (int ks = 0; ks < 4; ++ks) {
#pragma unroll
        for (int mt = 0; mt < 4; ++mt) {
          bf16x8 a = *(const bf16x8*)&xbf[(mt * 16 + l15) * XPAD + ks * 32 + q * 8];
          acc[mt][0] = __builtin_amdgcn_mfma_f32_16x16x32_bf16(a, B[ks][0], acc[mt][0], 0, 0, 0);
          acc[mt][1] = __builtin_amdgcn_mfma_f32_16x16x32_bf16(a, B[ks][1], acc[mt][1], 0, 0, 0);
        }
      }
#pragma unroll
      for (int mt = 0; mt < 4; ++mt) {
#pragma unroll
        for (int reg = 0; reg < 4; ++reg) {
          int rl = mt * 16 + q * 4 + reg;
          int row = row0 + rl;
          if (row < N) {
            size_t base = (size_t)row * NCH + n0;
            g[base + l15]      = f2bf(acc[mt][0][reg]);
            g[base + 16 + l15] = f2bf(acc[mt][1][reg]);
          }
        }
      }
    }
  } else {
    int ctid = tid - gbl * 256;
    int dd[EMAX];
    int ne = 0;
    for (long long e = ctid; e < E && ne < EMAX; e += CT)
      dd[ne++] = ei_at(ei, (long long)E + e, is64);
    for (int k = 0; k < ne; ++k) nranks[k] = atomicAdd(&counts[dd[k]], 1);
  }
  grid.sync();

  // -------- Phase C: decoupled-lookback scan (blocks 0..nb-1) --------
  const int nb = (N + SCAN_CHUNK - 1) / SCAN_CHUNK;
  if (b < nb) {
    int base = b * SCAN_CHUNK + t * 8;
    int v[8];
    int s = 0;
    if (base + 8 <= N) {
      const int4* p = (const int4*)(counts + base);
      int4 a = p[0], bb = p[1];
      v[0] = a.x; v[1] = a.y; v[2] = a.z; v[3] = a.w;
      v[4] = bb.x; v[5] = bb.y; v[6] = bb.z; v[7] = bb.w;
    } else {
#pragma unroll
      for (int j = 0; j < 8; ++j) {
        int i = base + j;
        v[j] = (i < N) ? counts[i] : 0;
      }
    }
#pragma unroll
    for (int j = 0; j < 8; ++j) s += v[j];
    int lane = t & 63, w = t >> 6;
    int incl = s;
#pragma unroll
    for (int off = 1; off < 64; off <<= 1) {
      int o = __shfl_up(incl, off);
      if (lane >= off) incl += o;
    }
    if (lane == 63) wsum[w] = incl;
    __syncthreads();
    if (t == 0) {
      int btot = (wsum[0] + wsum[1]) + (wsum[2] + wsum[3]);
      unsigned long long pub = (1ull << 63) | (unsigned int)btot;
      __hip_atomic_store(&flagsum[b], pub, __ATOMIC_RELEASE,
                         __HIP_MEMORY_SCOPE_AGENT);
      int acc = 0;
      for (int i = b - 1; i >= 0; --i) {
        unsigned long long fv;
        do {
          fv = __hip_atomic_load(&flagsum[i], __ATOMIC_ACQUIRE,
                                 __HIP_MEMORY_SCOPE_AGENT);
        } while (!(fv >> 63));
        acc += (int)(unsigned int)fv;
      }
      s_boff = acc;
    }
    __syncthreads();
    int woff = 0;
#pragma unroll
    for (int k = 0; k < 4; ++k)
      if (k < w) woff += wsum[k];
    int run = s_boff + woff + (incl - s);
#pragma unroll
    for (int j = 0; j < 8; ++j) {
      run += v[j];
      int i = base + j;
      if (i < N) {
        row_ptr[i + 1] = run;
        dis[i] = rsqrtf((float)(v[j] + 1));  // +1 self-loop; always > 0
      }
    }
    if (b == 0 && t == 0) row_ptr[0] = 0;
  }
  grid.sync();

  // -------- Phase D: fill (reg ranks) || scale g in place --------
  if (b < gbl) {
    for (int tile = b; tile < ntiles; tile += gbl) {
      int row0 = tile * GEMM_ROWS;
      for (int idx = t; idx < GEMM_ROWS * 16; idx += 256) {
        int r = idx >> 4, ch = idx & 15;
        int row = row0 + r;
        if (row < N) {
          float dl = dis[row];
          unsigned int* p = (unsigned int*)(g + (size_t)row * NCH + ch * 8);
          uint2 vv = *(uint2*)p;
          unsigned short h0 = f2bf(dl * __uint_as_float(vv.x << 16));
          unsigned short h1 = f2bf(dl * __uint_as_float(vv.x & 0xffff0000u));
          unsigned short h2 = f2bf(dl * __uint_as_float(vv.y << 16));
          unsigned short h3 = f2bf(dl * __uint_as_float(vv.y & 0xffff0000u));
          uint2 ov;
          ov.x = (unsigned int)h0 | ((unsigned int)h1 << 16);
          ov.y = (unsigned int)h2 | ((unsigned int)h3 << 16);
          *(uint2*)p = ov;
        }
      }
    }
  } else {
    int ctid = tid - gbl * 256;
    int ne = 0;
    for (long long e = ctid; e < E && ne < EMAX; e += CT, ++ne) {
      int s = ei_at(ei, e, is64);
      int d = ei_at(ei, (long long)E + e, is64);
      edge_src[row_ptr[d] + nranks[ne]] = s;
    }
  }
  grid.sync();

  // -------- Phase E: aggregate + bias + ReLU --------
  const int ngrp = (N + 3) / 4;
  for (int grp = b; grp < ngrp; grp += GRID) {
    int i = grp * 4 + (t >> 6);
    if (i >= N) continue;
    int lane = t & 63;
    int h = lane >> 5, sl = lane & 31;
    float a0 = 0.f, a1 = 0.f, a2 = 0.f, a3 = 0.f;
    if (h == 0) {
      uint2 v = *(const uint2*)(g + (size_t)i * NCH + sl * 4);
      a0 = __uint_as_float(v.x << 16);
      a1 = __uint_as_float(v.x & 0xffff0000u);
      a2 = __uint_as_float(v.y << 16);
      a3 = __uint_as_float(v.y & 0xffff0000u);
    }
    int e = row_ptr[i];
    int end = row_ptr[i + 1];
    for (; e + 8 <= end; e += 8) {
      int s0 = edge_src[e + h];
      int s1 = edge_src[e + 2 + h];
      int s2 = edge_src[e + 4 + h];
      int s3 = edge_src[e + 6 + h];
      uint2 v0 = *(const uint2*)(g + (size_t)s0 * NCH + sl * 4);
      uint2 v1 = *(const uint2*)(g + (size_t)s1 * NCH + sl * 4);
      uint2 v2 = *(const uint2*)(g + (size_t)s2 * NCH + sl * 4);
      uint2 v3 = *(const uint2*)(g + (size_t)s3 * NCH + sl * 4);
      a0 += (__uint_as_float(v0.x << 16) + __uint_as_float(v1.x << 16)) +
            (__uint_as_float(v2.x << 16) + __uint_as_float(v3.x << 16));
      a1 += (__uint_as_float(v0.x & 0xffff0000u) + __uint_as_float(v1.x & 0xffff0000u)) +
            (__uint_as_float(v2.x & 0xffff0000u) + __uint_as_float(v3.x & 0xffff0000u));
      a2 += (__uint_as_float(v0.y << 16) + __uint_as_float(v1.y << 16)) +
            (__uint_as_float(v2.y << 16) + __uint_as_float(v3.y << 16));
      a3 += (__uint_as_float(v0.y & 0xffff0000u) + __uint_as_float(v1.y & 0xffff0000u)) +
            (__uint_as_float(v2.y & 0xffff0000u) + __uint_as_float(v3.y & 0xffff0000u));
    }
    for (; e < end; e += 2) {
      int idx = e + h;
      if (idx < end) {
        uint2 v = *(const uint2*)(g + (size_t)edge_src[idx] * NCH + sl * 4);
        a0 += __uint_as_float(v.x << 16);
        a1 += __uint_as_float(v.x & 0xffff0000u);
        a2 += __uint_as_float(v.y << 16);
        a3 += __uint_as_float(v.y & 0xffff0000u);
      }
    }
    a0 += __shfl_xor(a0, 32);
    a1 += __shfl_xor(a1, 32);
    a2 += __shfl_xor(a2, 32);
    a3 += __shfl_xor(a3, 32);
    if (h == 0) {
      float di = dis[i];
      float4 bb = ((const float4*)bias)[sl];
      f32x4 o;
      o[0] = fmaxf(fmaf(a0, di, bb.x), 0.f);
      o[1] = fmaxf(fmaf(a1, di, bb.y), 0.f);
      o[2] = fmaxf(fmaf(a2, di, bb.z), 0.f);
      o[3] = fmaxf(fmaf(a3, di, bb.w), 0.f);
      __builtin_nontemporal_store(o, (f32x4*)(out + (size_t)i * NCH + sl * 4));
    }
  }
}

// ======================= fallback pipeline (R8, verified 180 µs) =======================
__global__ __launch_bounds__(256) void k_prep(const float* __restrict__ W,
                                              unsigned short* __restrict__ wt,
                                              int4* __restrict__ zbase, int nz4) {
  if ((int)blockIdx.x < 64) {
    int idx = blockIdx.x * 256 + threadIdx.x;
    int n = idx >> 7, k = idx & 127;
    wt[idx] = f2bf(W[k * NCH + n]);
  } else {
    int4 z = make_int4(0, 0, 0, 0);
    for (int i = (blockIdx.x - 64) * 256 + threadIdx.x; i < nz4; i += 16 * 256)
      zbase[i] = z;
  }
}

__global__ __launch_bounds__(256) void k_count(const void* __restrict__ ei, int E,
                                               int* __restrict__ counts,
                                               int* __restrict__ rank) {
  int is64 = detect_is64((const unsigned int*)ei);
  int e = blockIdx.x * 256 + threadIdx.x;
  if (e < E) {
    int d = ei_at(ei, (long long)E + e, is64);
    rank[e] = atomicAdd(&counts[d], 1);
  }
}

__global__ __launch_bounds__(256) void k_scan(const int* __restrict__ counts, int N,
                                              unsigned long long* __restrict__ flagsum,
                                              int* __restrict__ row_ptr,
                                              float* __restrict__ dis) {
  int t = threadIdx.x;
  int base = blockIdx.x * SCAN_CHUNK + t * 8;
  int v[8];
  int s = 0;
  if (base + 8 <= N) {
    const int4* p = (const int4*)(counts + base);
    int4 a = p[0], b = p[1];
    v[0] = a.x; v[1] = a.y; v[2] = a.z; v[3] = a.w;
    v[4] = b.x; v[5] = b.y; v[6] = b.z; v[7] = b.w;
  } else {
#pragma unroll
    for (int j = 0; j < 8; ++j) {
      int i = base + j;
      v[j] = (i < N) ? counts[i] : 0;
    }
  }
#pragma unroll
  for (int j = 0; j < 8; ++j) s += v[j];
  int lane = t & 63, w = t >> 6;
  int incl = s;
#pragma unroll
  for (int off = 1; off < 64; off <<= 1) {
    int o = __shfl_up(incl, off);
    if (lane >= off) incl += o;
  }
  __shared__ int wsum[4];
  __shared__ int s_boff;
  if (lane == 63) wsum[w] = incl;
  __syncthreads();
  if (t == 0) {
    int btot = (wsum[0] + wsum[1]) + (wsum[2] + wsum[3]);
    unsigned long long pub = (1ull << 63) | (unsigned int)btot;
    __hip_atomic_store(&flagsum[blockIdx.x], pub, __ATOMIC_RELEASE,
                       __HIP_MEMORY_SCOPE_AGENT);
    int acc = 0;
    for (int i = (int)blockIdx.x - 1; i >= 0; --i) {
      unsigned long long fv;
      do {
        fv = __hip_atomic_load(&flagsum[i], __ATOMIC_ACQUIRE,
                               __HIP_MEMORY_SCOPE_AGENT);
      } while (!(fv >> 63));
      acc += (int)(unsigned int)fv;
    }
    s_boff = acc;
  }
  __syncthreads();
  int woff = 0;
#pragma unroll
  for (int k = 0; k < 4; ++k)
    if (k < w) woff += wsum[k];
  int run = s_boff + woff + (incl - s);
#pragma unroll
  for (int j = 0; j < 8; ++j) {
    run += v[j];
    int i = base + j;
    if (i < N) {
      row_ptr[i + 1] = run;
      dis[i] = rsqrtf((float)(v[j] + 1));
    }
  }
  if (blockIdx.x == 0 && t == 0) row_ptr[0] = 0;
}

__global__ __launch_bounds__(256) void k_front(const float* __restrict__ x,
                                               const unsigned short* __restrict__ wt,
                                               const float* __restrict__ dis,
                                               unsigned short* __restrict__ g, int N,
                                               const void* __restrict__ ei, int E,
                                               const int* __restrict__ rank,
                                               const int* __restrict__ row_ptr,
                                               int* __restrict__ edge_src, int gbl) {
  if ((int)blockIdx.x >= gbl) {
    int is64 = detect_is64((const unsigned int*)ei);
    int e = (blockIdx.x - gbl) * 256 + threadIdx.x;
    if (e < E) {
      int s = ei_at(ei, e, is64);
      int d = ei_at(ei, (long long)E + e, is64);
      edge_src[row_ptr[d] + rank[e]] = s;
    }
    return;
  }
  __shared__ unsigned short xbf[GEMM_ROWS * XPAD];
  __shared__ float sdis[GEMM_ROWS];
  int t = threadIdx.x;
  int row0 = blockIdx.x * GEMM_ROWS;
#pragma unroll
  for (int j = 0; j < 8; ++j) {
    int idx = t + 256 * j;
    int r = idx >> 5, ch = idx & 31;
    int row = row0 + r;
    float4 v = (row < N) ? ((const float4*)(x + (size_t)row * NCH))[ch]
                         : make_float4(0.f, 0.f, 0.f, 0.f);
    ushort4 p;
    p.x = f2bf(v.x); p.y = f2bf(v.y); p.z = f2bf(v.z); p.w = f2bf(v.w);
    *(ushort4*)&xbf[r * XPAD + ch * 4] = p;
  }
  if (t < GEMM_ROWS) {
    int row = row0 + t;
    sdis[t] = (row < N) ? dis[row] : 0.f;
  }
  int lane = t & 63, wv = t >> 6;
  int n0 = wv * 32, l15 = lane & 15, q = lane >> 4;
  bf16x8 B[4][2];
#pragma unroll
  for (int ks = 0; ks < 4; ++ks)
#pragma unroll
    for (int nt = 0; nt < 2; ++nt) {
      int n = n0 + nt * 16 + l15;
      B[ks][nt] = *(const bf16x8*)(wt + (size_t)n * NCH + ks * 32 + q * 8);
    }
  __syncthreads();
  f32x4 acc[4][2];
#pragma unroll
  for (int mt = 0; mt < 4; ++mt)
#pragma unroll
    for (int nt = 0; nt < 2; ++nt)
#pragma unroll
      for (int i = 0; i < 4; ++i) acc[mt][nt][i] = 0.f;
#pragma unroll
  for (int ks = 0; ks < 4; ++ks) {
#pragma unroll
    for (int mt = 0; mt < 4; ++mt) {
      bf16x8 a = *(const bf16x8*)&xbf[(mt * 16 + l15) * XPAD + ks * 32 + q * 8];
      acc[mt][0] = __builtin_amdgcn_mfma_f32_16x16x32_bf16(a, B[ks][0], acc[mt][0], 0, 0, 0);
      acc[mt][1] = __builtin_amdgcn_mfma_f32_16x16x32_bf16(a, B[ks][1], acc[mt][1], 0, 0, 0);
    }
  }
#pragma unroll
  for (int mt = 0; mt < 4; ++mt) {
#pragma unroll
    for (int reg = 0; reg < 4; ++reg) {
      int rl = mt * 16 + q * 4 + reg;
      int row = row0 + rl;
      if (row < N) {
        float dl = sdis[rl];
        size_t base = (size_t)row * NCH + n0;
        g[base + l15]      = f2bf(acc[mt][0][reg] * dl);
        g[base + 16 + l15] = f2bf(acc[mt][1][reg] * dl);
      }
    }
  }
}

__global__ __launch_bounds__(256) void k_agg(const unsigned short* __restrict__ g,
                                             const int* __restrict__ row_ptr,
                                             const int* __restrict__ edge_src,
                                             const float* __restrict__ dis,
                                             const float* __restrict__ bias,
                                             float* __restrict__ out, int N) {
  int i = blockIdx.x * 4 + (threadIdx.x >> 6);
  if (i >= N) return;
  int lane = threadIdx.x & 63;
  int h = lane >> 5, sl = lane & 31;
  float a0 = 0.f, a1 = 0.f, a2 = 0.f, a3 = 0.f;
  if (h == 0) {
    uint2 v = *(const uint2*)(g + (size_t)i * NCH + sl * 4);
    a0 = __uint_as_float(v.x << 16);
    a1 = __uint_as_float(v.x & 0xffff0000u);
    a2 = __uint_as_float(v.y << 16);
    a3 = __uint_as_float(v.y & 0xffff0000u);
  }
  int e = row_ptr[i];
  int end = row_ptr[i + 1];
  for (; e + 8 <= end; e += 8) {
    int s0 = edge_src[e + h];
    int s1 = edge_src[e + 2 + h];
    int s2 = edge_src[e + 4 + h];
    int s3 = edge_src[e + 6 + h];
    uint2 v0 = *(const uint2*)(g + (size_t)s0 * NCH + sl * 4);
    uint2 v1 = *(const uint2*)(g + (size_t)s1 * NCH + sl * 4);
    uint2 v2 = *(const uint2*)(g + (size_t)s2 * NCH + sl * 4);
    uint2 v3 = *(const uint2*)(g + (size_t)s3 * NCH + sl * 4);
    a0 += (__uint_as_float(v0.x << 16) + __uint_as_float(v1.x << 16)) +
          (__uint_as_float(v2.x << 16) + __uint_as_float(v3.x << 16));
    a1 += (__uint_as_float(v0.x & 0xffff0000u) + __uint_as_float(v1.x & 0xffff0000u)) +
          (__uint_as_float(v2.x & 0xffff0000u) + __uint_as_float(v3.x & 0xffff0000u));
    a2 += (__uint_as_float(v0.y << 16) + __uint_as_float(v1.y << 16)) +
          (__uint_as_float(v2.y << 16) + __uint_as_float(v3.y << 16));
    a3 += (__uint_as_float(v0.y & 0xffff0000u) + __uint_as_float(v1.y & 0xffff0000u)) +
          (__uint_as_float(v2.y & 0xffff0000u) + __uint_as_float(v3.y & 0xffff0000u));
  }
  for (; e < end; e += 2) {
    int idx = e + h;
    if (idx < end) {
      uint2 v = *(const uint2*)(g + (size_t)edge_src[idx] * NCH + sl * 4);
      a0 += __uint_as_float(v.x << 16);
      a1 += __uint_as_float(v.x & 0xffff0000u);
      a2 += __uint_as_float(v.y << 16);
      a3 += __uint_as_float(v.y & 0xffff0000u);
    }
  }
  a0 += __shfl_xor(a0, 32);
  a1 += __shfl_xor(a1, 32);
  a2 += __shfl_xor(a2, 32);
  a3 += __shfl_xor(a3, 32);
  if (h == 0) {
    float di = dis[i];
    float4 bb = ((const float4*)bias)[sl];
    f32x4 o;
    o[0] = fmaxf(fmaf(a0, di, bb.x), 0.f);
    o[1] = fmaxf(fmaf(a1, di, bb.y), 0.f);
    o[2] = fmaxf(fmaf(a2, di, bb.z), 0.f);
    o[3] = fmaxf(fmaf(a3, di, bb.w), 0.f);
    __builtin_nontemporal_store(o, (f32x4*)(out + (size_t)i * NCH + sl * 4));
  }
}

extern "C" void kernel_launch(void* const* d_in, const int* in_sizes, int n_in,
                              void* d_out, int out_size, void* d_ws, size_t ws_size,
                              hipStream_t stream) {
  const float* x    = (const float*)d_in[0];
  const void*  ei   = d_in[1];
  const float* W    = (const float*)d_in[2];
  const float* bias = (const float*)d_in[3];
  float* out = (float*)d_out;

  int N = out_size / NCH;       // 50000
  int E = in_sizes[1] / 2;      // 800000

  char* ws = (char*)d_ws;
  size_t off = 0;
  auto alloc = [&](size_t bytes) -> char* {
    char* p = ws + off;
    off = (off + bytes + 255) & ~(size_t)255;
    return p;
  };
  char* zbase = ws;  // zero region for fallback k_prep: counts + flagsum
  int*                counts   = (int*)alloc((size_t)N * 4);
  unsigned long long* flagsum  = (unsigned long long*)alloc(1024);
  size_t zbytes = off;
  int*                row_ptr  = (int*)alloc((size_t)(N + 1) * 4);
  float*              dis      = (float*)alloc((size_t)N * 4);
  unsigned short*     wt       = (unsigned short*)alloc((size_t)NCH * NCH * 2);
  int*                rank     = (int*)alloc((size_t)E * 4);
  int*                edge_src = (int*)alloc((size_t)E * 4);
  unsigned short*     g        = (unsigned short*)alloc((size_t)N * NCH * 2);
  (void)ws_size;

  int nb     = (N + SCAN_CHUNK - 1) / SCAN_CHUNK;   // 25
  int ntiles = (N + GEMM_ROWS - 1) / GEMM_ROWS;     // 782
  int gbl = ntiles;
  if (gbl > GRID - 242) gbl = GRID - 242;           // keep >=242 count blocks (EMAX bound)
  int cbl = (E + 255) / 256;

  // Host-side occupancy check (capture-safe, deterministic): only take the
  // cooperative path if 4 blocks/CU actually fit (1024 co-resident blocks).
  int coopBlocks = 0;
  hipError_t qerr = hipOccupancyMaxActiveBlocksPerMultiprocessor(
      &coopBlocks, (const void*)k_mega, 256, 0);
  bool coop_ok = (qerr == hipSuccess && coopBlocks >= 4);

  if (coop_ok) {
    void* args[] = {(void*)&x, (void*)&ei, (void*)&W, (void*)&bias, (void*)&out,
                    (void*)&N, (void*)&E, (void*)&ntiles, (void*)&gbl,
                    (void*)&counts, (void*)&flagsum, (void*)&row_ptr, (void*)&dis,
                    (void*)&wt, (void*)&edge_src, (void*)&g};
    hipError_t lerr = hipLaunchCooperativeKernel((const void*)k_mega, dim3(GRID),
                                                 dim3(256), args, 0, stream);
    if (lerr == hipSuccess) return;
  }

  // Fallback: verified R8 pipeline.
  int fgbl = ntiles;
  k_prep<<<80, 256, 0, stream>>>(W, wt, (int4*)zbase, (int)(zbytes / 16));
  k_count<<<cbl, 256, 0, stream>>>(ei, E, counts, rank);
  k_scan<<<nb, 256, 0, stream>>>(counts, N, flagsum, row_ptr, dis);
  k_front<<<fgbl + cbl, 256, 0, stream>>>(x, wt, dis, g, N, ei, E, rank, row_ptr,
                                          edge_src, fgbl);
  k_agg<<<(N + 3) / 4, 256, 0, stream>>>(g, row_ptr, edge_src, dis, bias, out, N);
}

// Round 11
// 176.970 us; speedup vs baseline: 1.1706x; 1.0152x over previous
//
#include <hip/hip_runtime.h>
#include <cstdint>
#include <cstddef>

#define NCH 128
#define SCAN_CHUNK 2048  // 256 threads x 8 elems
#define GEMM_ROWS 64
#define XPAD 136         // 128 + 8 bf16 pad: A-frag ds_read_b128 conflict-free

typedef short bf16x8 __attribute__((ext_vector_type(8)));
typedef float f32x4 __attribute__((ext_vector_type(4)));

__device__ __forceinline__ int detect_is64(const unsigned int* __restrict__ ei) {
  // int64 edge_index with ids < 2^31 -> all odd 32-bit words zero. Wave-uniform;
  // call with all lanes active (kernel top, before divergence).
  unsigned int v = ei[((threadIdx.x & 63) << 1) + 1];
  return (__ballot(v != 0u) == 0ULL) ? 1 : 0;
}

__device__ __forceinline__ unsigned short f2bf(float x) {
  unsigned int u = __float_as_uint(x);
  u += 0x7fffu + ((u >> 16) & 1u);  // RNE
  return (unsigned short)(u >> 16);
}

__device__ __forceinline__ int ei_at(const void* ei, long long i, int is64) {
  return is64 ? (int)((const long long*)ei)[i] : ((const int*)ei)[i];
}

// Degree count (1 edge/thread, rank kept for atomic-free fill later).
// Blocks >= cbl transpose W -> bf16 wt[n][k] (MFMA B operand), hiding that
// 64-block job under the count's memory time.
__global__ __launch_bounds__(256) void k_count(const void* __restrict__ ei, int E,
                                               int cbl, int* __restrict__ counts,
                                               int* __restrict__ rank,
                                               const float* __restrict__ W,
                                               unsigned short* __restrict__ wt) {
  if ((int)blockIdx.x >= cbl) {
    int idx = (blockIdx.x - cbl) * 256 + threadIdx.x;  // 0..16383
    int n = idx >> 7, k = idx & 127;
    wt[idx] = f2bf(W[k * NCH + n]);
    return;
  }
  int is64 = detect_is64((const unsigned int*)ei);
  int e = blockIdx.x * 256 + threadIdx.x;
  if (e < E) {
    int d = ei_at(ei, (long long)E + e, is64);
    rank[e] = atomicAdd(&counts[d], 1);
  }
}

// Single-pass exclusive scan (decoupled lookback): row_ptr[i+1],
// dis[i] = rsqrt(deg+1).
__global__ __launch_bounds__(256) void k_scan(const int* __restrict__ counts, int N,
                                              unsigned long long* __restrict__ flagsum,
                                              int* __restrict__ row_ptr,
                                              float* __restrict__ dis) {
  int t = threadIdx.x;
  int base = blockIdx.x * SCAN_CHUNK + t * 8;
  int v[8];
  int s = 0;
  if (base + 8 <= N) {
    const int4* p = (const int4*)(counts + base);
    int4 a = p[0], b = p[1];
    v[0] = a.x; v[1] = a.y; v[2] = a.z; v[3] = a.w;
    v[4] = b.x; v[5] = b.y; v[6] = b.z; v[7] = b.w;
  } else {
#pragma unroll
    for (int j = 0; j < 8; ++j) {
      int i = base + j;
      v[j] = (i < N) ? counts[i] : 0;
    }
  }
#pragma unroll
  for (int j = 0; j < 8; ++j) s += v[j];
  int lane = t & 63, w = t >> 6;
  int incl = s;
#pragma unroll
  for (int off = 1; off < 64; off <<= 1) {
    int o = __shfl_up(incl, off);
    if (lane >= off) incl += o;
  }
  __shared__ int wsum[4];
  __shared__ int s_boff;
  if (lane == 63) wsum[w] = incl;
  __syncthreads();
  if (t == 0) {
    int btot = (wsum[0] + wsum[1]) + (wsum[2] + wsum[3]);
    unsigned long long pub = (1ull << 63) | (unsigned int)btot;
    __hip_atomic_store(&flagsum[blockIdx.x], pub, __ATOMIC_RELEASE,
                       __HIP_MEMORY_SCOPE_AGENT);
    int acc = 0;
    for (int i = (int)blockIdx.x - 1; i >= 0; --i) {
      unsigned long long fv;
      do {
        fv = __hip_atomic_load(&flagsum[i], __ATOMIC_ACQUIRE,
                               __HIP_MEMORY_SCOPE_AGENT);
      } while (!(fv >> 63));
      acc += (int)(unsigned int)fv;
    }
    s_boff = acc;
  }
  __syncthreads();
  int woff = 0;
#pragma unroll
  for (int k = 0; k < 4; ++k)
    if (k < w) woff += wsum[k];
  int run = s_boff + woff + (incl - s);
#pragma unroll
  for (int j = 0; j < 8; ++j) {
    run += v[j];
    int i = base + j;
    if (i < N) {
      row_ptr[i + 1] = run;
      dis[i] = rsqrtf((float)(v[j] + 1));  // +1 self-loop; always > 0
    }
  }
  if (blockIdx.x == 0 && t == 0) row_ptr[0] = 0;
}

// Fused: blocks [0,gbl) = MFMA GEMM g[i,:]=bf16(dis[i]*(x@W)); blocks [gbl,..)
// = rank-based CSR fill (no atomics). MFMA pipe overlaps fill's scatter time.
__global__ __launch_bounds__(256) void k_front(const float* __restrict__ x,
                                               const unsigned short* __restrict__ wt,
                                               const float* __restrict__ dis,
                                               unsigned short* __restrict__ g, int N,
                                               const void* __restrict__ ei, int E,
                                               const int* __restrict__ rank,
                                               const int* __restrict__ row_ptr,
                                               int* __restrict__ edge_src, int gbl) {
  if ((int)blockIdx.x >= gbl) {
    int is64 = detect_is64((const unsigned int*)ei);
    int e = (blockIdx.x - gbl) * 256 + threadIdx.x;
    if (e < E) {
      int s = ei_at(ei, e, is64);
      int d = ei_at(ei, (long long)E + e, is64);
      edge_src[row_ptr[d] + rank[e]] = s;
    }
    return;
  }
  __shared__ unsigned short xbf[GEMM_ROWS * XPAD];
  __shared__ float sdis[GEMM_ROWS];
  int t = threadIdx.x;
  int row0 = blockIdx.x * GEMM_ROWS;
#pragma unroll
  for (int j = 0; j < 8; ++j) {
    int idx = t + 256 * j;
    int r = idx >> 5, ch = idx & 31;
    int row = row0 + r;
    float4 v = (row < N) ? ((const float4*)(x + (size_t)row * NCH))[ch]
                         : make_float4(0.f, 0.f, 0.f, 0.f);
    ushort4 p;
    p.x = f2bf(v.x); p.y = f2bf(v.y); p.z = f2bf(v.z); p.w = f2bf(v.w);
    *(ushort4*)&xbf[r * XPAD + ch * 4] = p;
  }
  if (t < GEMM_ROWS) {
    int row = row0 + t;
    sdis[t] = (row < N) ? dis[row] : 0.f;
  }
  int lane = t & 63, wv = t >> 6;
  int n0 = wv * 32, l15 = lane & 15, q = lane >> 4;
  bf16x8 B[4][2];
#pragma unroll
  for (int ks = 0; ks < 4; ++ks)
#pragma unroll
    for (int nt = 0; nt < 2; ++nt) {
      int n = n0 + nt * 16 + l15;
      B[ks][nt] = *(const bf16x8*)(wt + (size_t)n * NCH + ks * 32 + q * 8);
    }
  __syncthreads();
  f32x4 acc[4][2];
#pragma unroll
  for (int mt = 0; mt < 4; ++mt)
#pragma unroll
    for (int nt = 0; nt < 2; ++nt)
#pragma unroll
      for (int i = 0; i < 4; ++i) acc[mt][nt][i] = 0.f;
#pragma unroll
  for (int ks = 0; ks < 4; ++ks) {
#pragma unroll
    for (int mt = 0; mt < 4; ++mt) {
      bf16x8 a = *(const bf16x8*)&xbf[(mt * 16 + l15) * XPAD + ks * 32 + q * 8];
      acc[mt][0] = __builtin_amdgcn_mfma_f32_16x16x32_bf16(a, B[ks][0], acc[mt][0], 0, 0, 0);
      acc[mt][1] = __builtin_amdgcn_mfma_f32_16x16x32_bf16(a, B[ks][1], acc[mt][1], 0, 0, 0);
    }
  }
#pragma unroll
  for (int mt = 0; mt < 4; ++mt) {
#pragma unroll
    for (int reg = 0; reg < 4; ++reg) {
      int rl = mt * 16 + q * 4 + reg;
      int row = row0 + rl;
      if (row < N) {
        float dl = sdis[rl];
        size_t base = (size_t)row * NCH + n0;
        g[base + l15]      = f2bf(acc[mt][0][reg] * dl);
        g[base + 16 + l15] = f2bf(acc[mt][1][reg] * dl);
      }
    }
  }
}

// One wave per node; lane L: half h=L>>5 (edges e+2j+h), sublane sl=L&31 ->
// channels [4sl,4sl+4) as uint2. 16-edge main loop = 8 g-loads in flight per
// half (MLP probe: if this is neutral vs R8's 8-edge loop, agg is L3-BW-bound).
__global__ __launch_bounds__(256) void k_agg(const unsigned short* __restrict__ g,
                                             const int* __restrict__ row_ptr,
                                             const int* __restrict__ edge_src,
                                             const float* __restrict__ dis,
                                             const float* __restrict__ bias,
                                             float* __restrict__ out, int N) {
  int i = blockIdx.x * 4 + (threadIdx.x >> 6);
  if (i >= N) return;
  int lane = threadIdx.x & 63;
  int h = lane >> 5, sl = lane & 31;
  float a0 = 0.f, a1 = 0.f, a2 = 0.f, a3 = 0.f;
  if (h == 0) {
    uint2 v = *(const uint2*)(g + (size_t)i * NCH + sl * 4);
    a0 = __uint_as_float(v.x << 16);
    a1 = __uint_as_float(v.x & 0xffff0000u);
    a2 = __uint_as_float(v.y << 16);
    a3 = __uint_as_float(v.y & 0xffff0000u);
  }
  int e = row_ptr[i];
  int end = row_ptr[i + 1];
  for (; e + 16 <= end; e += 16) {
    int s[8];
#pragma unroll
    for (int j = 0; j < 8; ++j) s[j] = edge_src[e + 2 * j + h];
    uint2 v[8];
#pragma unroll
    for (int j = 0; j < 8; ++j) v[j] = *(const uint2*)(g + (size_t)s[j] * NCH + sl * 4);
#pragma unroll
    for (int j = 0; j < 8; ++j) {
      a0 += __uint_as_float(v[j].x << 16);
      a1 += __uint_as_float(v[j].x & 0xffff0000u);
      a2 += __uint_as_float(v[j].y << 16);
      a3 += __uint_as_float(v[j].y & 0xffff0000u);
    }
  }
  for (; e + 8 <= end; e += 8) {
    int s[4];
#pragma unroll
    for (int j = 0; j < 4; ++j) s[j] = edge_src[e + 2 * j + h];
    uint2 v[4];
#pragma unroll
    for (int j = 0; j < 4; ++j) v[j] = *(const uint2*)(g + (size_t)s[j] * NCH + sl * 4);
#pragma unroll
    for (int j = 0; j < 4; ++j) {
      a0 += __uint_as_float(v[j].x << 16);
      a1 += __uint_as_float(v[j].x & 0xffff0000u);
      a2 += __uint_as_float(v[j].y << 16);
      a3 += __uint_as_float(v[j].y & 0xffff0000u);
    }
  }
  for (; e < end; e += 2) {
    int idx = e + h;
    if (idx < end) {
      uint2 v = *(const uint2*)(g + (size_t)edge_src[idx] * NCH + sl * 4);
      a0 += __uint_as_float(v.x << 16);
      a1 += __uint_as_float(v.x & 0xffff0000u);
      a2 += __uint_as_float(v.y << 16);
      a3 += __uint_as_float(v.y & 0xffff0000u);
    }
  }
  a0 += __shfl_xor(a0, 32);
  a1 += __shfl_xor(a1, 32);
  a2 += __shfl_xor(a2, 32);
  a3 += __shfl_xor(a3, 32);
  if (h == 0) {
    float di = dis[i];
    float4 bb = ((const float4*)bias)[sl];
    f32x4 o;
    o[0] = fmaxf(fmaf(a0, di, bb.x), 0.f);
    o[1] = fmaxf(fmaf(a1, di, bb.y), 0.f);
    o[2] = fmaxf(fmaf(a2, di, bb.z), 0.f);
    o[3] = fmaxf(fmaf(a3, di, bb.w), 0.f);
    __builtin_nontemporal_store(o, (f32x4*)(out + (size_t)i * NCH + sl * 4));
  }
}

extern "C" void kernel_launch(void* const* d_in, const int* in_sizes, int n_in,
                              void* d_out, int out_size, void* d_ws, size_t ws_size,
                              hipStream_t stream) {
  const float* x    = (const float*)d_in[0];
  const void*  ei   = d_in[1];
  const float* W    = (const float*)d_in[2];
  const float* bias = (const float*)d_in[3];
  float* out = (float*)d_out;

  int N = out_size / NCH;       // 50000
  int E = in_sizes[1] / 2;      // 800000

  char* ws = (char*)d_ws;
  size_t off = 0;
  auto alloc = [&](size_t bytes) -> char* {
    char* p = ws + off;
    off = (off + bytes + 255) & ~(size_t)255;
    return p;
  };
  char* zbase = ws;  // zero region: counts + flagsum (one small memset)
  int*                counts   = (int*)alloc((size_t)N * 4);
  unsigned long long* flagsum  = (unsigned long long*)alloc(1024);
  size_t zbytes = off;
  int*                row_ptr  = (int*)alloc((size_t)(N + 1) * 4);
  float*              dis      = (float*)alloc((size_t)N * 4);
  unsigned short*     wt       = (unsigned short*)alloc((size_t)NCH * NCH * 2);
  int*                rank     = (int*)alloc((size_t)E * 4);
  int*                edge_src = (int*)alloc((size_t)E * 4);
  unsigned short*     g        = (unsigned short*)alloc((size_t)N * NCH * 2);
  (void)ws_size;

  int nb  = (N + SCAN_CHUNK - 1) / SCAN_CHUNK;  // 25
  int gbl = (N + GEMM_ROWS - 1) / GEMM_ROWS;    // 782 gemm blocks
  int cbl = (E + 255) / 256;                    // 3125 count/fill blocks

  (void)hipMemsetAsync(zbase, 0, zbytes, stream);
  k_count<<<cbl + 64, 256, 0, stream>>>(ei, E, cbl, counts, rank, W, wt);
  k_scan<<<nb, 256, 0, stream>>>(counts, N, flagsum, row_ptr, dis);
  k_front<<<gbl + cbl, 256, 0, stream>>>(x, wt, dis, g, N, ei, E, rank, row_ptr,
                                         edge_src, gbl);
  k_agg<<<(N + 3) / 4, 256, 0, stream>>>(g, row_ptr, edge_src, dis, bias, out, N);
}